// Round 1
// baseline (964.369 us; speedup 1.0000x reference)
//
#include <hip/hip_runtime.h>
#include <math.h>

#define NN_ 1024
#define C1_ 384
#define DOUT_ 2112
#define NOUT_ 384

// ---------------- K1: projections + rotation + sq/sk ----------------
// block handles 8 rows of n; 256 threads
__global__ __launch_bounds__(256) void k_proj(
    const float* __restrict__ in1, const float* __restrict__ rotm, const float* __restrict__ trans,
    const float* __restrict__ wq, const float* __restrict__ bq,
    const float* __restrict__ wkv, const float* __restrict__ bkv,
    const float* __restrict__ wqp, const float* __restrict__ bqp,
    const float* __restrict__ wkvp, const float* __restrict__ bkvp,
    float* __restrict__ qs, float* __restrict__ ks, float* __restrict__ vs,
    float* __restrict__ qp, float* __restrict__ kp, float* __restrict__ vp,
    float* __restrict__ sq, float* __restrict__ sk)
{
    __shared__ float in1_l[8][C1_];
    __shared__ float praw[8][576];   // [0..143] = q raw (c*48+k), [144..575] = kv raw (c*144+k)
    __shared__ float rt_l[8][12];    // 9 rot + 3 trans
    const int t = threadIdx.x;
    const int n0 = blockIdx.x * 8;

    #pragma unroll
    for (int r = 0; r < 3; ++r) {
        int f4 = t + 256 * r;            // 768 float4 = 8*384 floats
        int nn = f4 / 96, c4 = f4 % 96;
        float4 v = *(const float4*)(in1 + (size_t)(n0 + nn) * C1_ + c4 * 4);
        *(float4*)(&in1_l[nn][c4 * 4]) = v;
    }
    if (t < 96) {
        int nn = t / 12, i = t % 12;
        rt_l[nn][i] = (i < 9) ? rotm[(n0 + nn) * 9 + i] : trans[(n0 + nn) * 3 + i - 9];
    }
    __syncthreads();

    for (int it = 0; it < 5; ++it) {
        int col = t + it * 256;
        if (col >= 1152) break;
        const float* w; int ncol, j; float b;
        if (col < 192)      { w = wq;   ncol = 192; j = col;       b = bq[j]; }
        else if (col < 576) { w = wkv;  ncol = 384; j = col - 192; b = bkv[j]; }
        else if (col < 720) { w = wqp;  ncol = 144; j = col - 576; b = bqp[j]; }
        else                { w = wkvp; ncol = 432; j = col - 720; b = bkvp[j]; }
        float acc[8];
        #pragma unroll
        for (int nn = 0; nn < 8; ++nn) acc[nn] = b;
        for (int c = 0; c < C1_; ++c) {
            float wv = w[(size_t)c * ncol + j];
            #pragma unroll
            for (int nn = 0; nn < 8; ++nn) acc[nn] += in1_l[nn][c] * wv;
        }
        #pragma unroll
        for (int nn = 0; nn < 8; ++nn) {
            int n = n0 + nn;
            if (col < 192) qs[(size_t)n * 192 + col] = acc[nn];
            else if (col < 576) {
                int h = j >> 5, r2 = j & 31;
                if (r2 < 16) ks[(size_t)n * 192 + h * 16 + r2] = acc[nn];
                else         vs[(size_t)n * 192 + h * 16 + r2 - 16] = acc[nn];
            }
            else if (col < 720) praw[nn][j] = acc[nn];
            else                praw[nn][144 + j] = acc[nn];
        }
    }
    __syncthreads();

    // rotation: 8*576 = 4608 outputs
    for (int r = 0; r < 18; ++r) {
        int idx = t + 256 * r;
        int nn = idx / 576, j = idx % 576;
        const float* R = rt_l[nn];
        if (j < 144) {
            int a = j / 48, k = j % 48;
            float v = R[9 + a] + R[a*3+0]*praw[nn][k] + R[a*3+1]*praw[nn][48+k] + R[a*3+2]*praw[nn][96+k];
            qp[(size_t)(n0 + nn) * 144 + j] = v;
        } else {
            int j2 = j - 144; int a = j2 / 144, k = j2 % 144;
            float v = R[9 + a] + R[a*3+0]*praw[nn][144+k] + R[a*3+1]*praw[nn][288+k] + R[a*3+2]*praw[nn][432+k];
            int h = k / 12, jj = k % 12;
            if (jj < 4) kp[(size_t)(n0 + nn) * 144 + a * 48 + h * 4 + jj] = v;
            else        vp[(size_t)(n0 + nn) * 288 + a * 96 + h * 8 + (jj - 4)] = v;
        }
    }
    // sq/sk (recompute rotated comps from praw; cheap)
    if (t < 192) {
        int nn = t / 24, r2 = t % 24, h = r2 % 12, which = r2 / 12;
        const float* R = rt_l[nn];
        float s = 0.f;
        #pragma unroll
        for (int a = 0; a < 3; ++a) {
            #pragma unroll
            for (int p = 0; p < 4; ++p) {
                float v;
                if (which == 0) {
                    int k = h * 4 + p;
                    v = R[9+a] + R[a*3+0]*praw[nn][k] + R[a*3+1]*praw[nn][48+k] + R[a*3+2]*praw[nn][96+k];
                } else {
                    int k = h * 12 + p;
                    v = R[9+a] + R[a*3+0]*praw[nn][144+k] + R[a*3+1]*praw[nn][288+k] + R[a*3+2]*praw[nn][432+k];
                }
                s += v * v;
            }
        }
        if (which == 0) sq[(size_t)(n0 + nn) * 12 + h] = s;
        else            sk[(size_t)(n0 + nn) * 12 + h] = s;
    }
}

// ---------------- K2: fused flash IPA, one block per query row n ----------------
__global__ __launch_bounds__(256) void k_attn(
    const float* __restrict__ x2d, const float* __restrict__ mask,
    const float* __restrict__ rotm, const float* __restrict__ trans,
    const float* __restrict__ w2d, const float* __restrict__ b2d, const float* __restrict__ tpw,
    const float* __restrict__ qs, const float* __restrict__ ks, const float* __restrict__ vs,
    const float* __restrict__ qp, const float* __restrict__ kp, const float* __restrict__ vp,
    const float* __restrict__ sq, const float* __restrict__ sk,
    float* __restrict__ fin)
{
    __shared__ float x_l[128 * 65];      // [c][m], stride 65 (bank = (c+m)%32)
    __shared__ float w2_l[12 * 128];     // [h][c]
    __shared__ float tl[12 * 66];        // logits -> p, [h][m]
    __shared__ float qs_l[192];
    __shared__ float qp_l[144];
    __shared__ float sq_l[12], b2_l[12], pw_l[12];
    __shared__ float rmax[12], rsum[12], alph[12], nmx[12];
    __shared__ float rt_l[12];
    __shared__ float pg_l[288];

    const int t = threadIdx.x;
    const int n = blockIdx.x;

    #pragma unroll
    for (int r = 0; r < 6; ++r) { int idx = t + 256 * r; int c = idx / 12, h = idx % 12; w2_l[h * 128 + c] = w2d[idx]; }
    if (t < 192) qs_l[t] = qs[(size_t)n * 192 + t];
    if (t < 144) qp_l[t] = qp[(size_t)n * 144 + t];
    if (t < 12) {
        sq_l[t] = sq[(size_t)n * 12 + t];
        b2_l[t] = b2d[t];
        pw_l[t] = 0.13608276348795434f * log1pf(expf(tpw[t]));  // sqrt(1/54)*softplus
        rmax[t] = -3.0e38f; rsum[t] = 0.f;
    }
    if (t < 9) rt_l[t] = rotm[n * 9 + t];
    if (t >= 9 && t < 12) rt_l[t] = trans[n * 3 + t - 9];
    const float mask_n = mask[n];

    const int m_ = t >> 2, q_ = t & 3;        // staging/logits: 64 m x 4 c-quarters
    const int h0 = (t >> 6) * 3, cc = t & 63; // res_2d accumulation mapping
    const int j0 = 2 * t;                     // res_scalar/res_pg mapping (t<240)
    int hF0 = 0, hF1 = 0;
    if (t < 240) {
        hF0 = (j0 < 192) ? (j0 >> 4) : (((j0 - 192) % 96) >> 3);
        hF1 = (j0 + 1 < 192) ? ((j0 + 1) >> 4) : (((j0 + 1 - 192) % 96) >> 3);
    }
    float acc2[3][2] = {{0.f,0.f},{0.f,0.f},{0.f,0.f}};
    float accF[2] = {0.f, 0.f};
    __syncthreads();

    for (int m0 = 0; m0 < NN_; m0 += 64) {
        // -------- phase A: stage x tile (transposed) + att2d partials + logits --------
        float at2[12];
        #pragma unroll
        for (int h = 0; h < 12; ++h) at2[h] = 0.f;
        const float* xrow = x2d + ((size_t)n * NN_ + (m0 + m_)) * 128;
        #pragma unroll
        for (int i = 0; i < 8; ++i) {
            int c = 16 * i + 4 * q_;
            float4 xv = *(const float4*)(xrow + c);
            x_l[(c + 0) * 65 + m_] = xv.x;
            x_l[(c + 1) * 65 + m_] = xv.y;
            x_l[(c + 2) * 65 + m_] = xv.z;
            x_l[(c + 3) * 65 + m_] = xv.w;
            #pragma unroll
            for (int h = 0; h < 12; ++h) {
                float4 wv = *(const float4*)(&w2_l[h * 128 + c]);
                at2[h] += xv.x * wv.x + xv.y * wv.y + xv.z * wv.z + xv.w * wv.w;
            }
        }
        #pragma unroll
        for (int h = 0; h < 12; ++h) {
            at2[h] += __shfl_xor(at2[h], 1);
            at2[h] += __shfl_xor(at2[h], 2);
        }
        {
            const int mg = m0 + m_;
            const float mk = 100000.0f * (1.0f - mask_n * mask[mg]);
            #pragma unroll
            for (int e = 0; e < 3; ++e) {
                int h = q_ * 3 + e;
                const float4* ksr = (const float4*)(ks + (size_t)mg * 192 + h * 16);
                const float4* qsr = (const float4*)(&qs_l[h * 16]);
                float d = 0.f;
                #pragma unroll
                for (int s4 = 0; s4 < 4; ++s4) {
                    float4 a = qsr[s4], b = ksr[s4];
                    d += a.x * b.x + a.y * b.y + a.z * b.z + a.w * b.w;
                }
                float qk = 0.f;
                #pragma unroll
                for (int a = 0; a < 3; ++a) {
                    float4 kv = *(const float4*)(kp + (size_t)mg * 144 + a * 48 + h * 4);
                    float4 qv = *(const float4*)(&qp_l[a * 48 + h * 4]);
                    qk += qv.x * kv.x + qv.y * kv.y + qv.z * kv.z + qv.w * kv.w;
                }
                float dist2 = sq_l[h] + sk[(size_t)mg * 12 + h] - 2.f * qk;
                float l = 0.14433756729740643f * d
                        - 0.5f * pw_l[h] * dist2
                        + 0.57735026918962576f * (at2[h] + b2_l[h])
                        - mk;
                tl[h * 66 + m_] = l;
            }
        }
        __syncthreads();
        // -------- phase B: online softmax update --------
        if (t < 12) {
            float tm = -3.0e38f;
            for (int m = 0; m < 64; ++m) tm = fmaxf(tm, tl[t * 66 + m]);
            float nm = fmaxf(rmax[t], tm);
            alph[t] = __expf(rmax[t] - nm);
            rmax[t] = nm; nmx[t] = nm;
        }
        __syncthreads();
        #pragma unroll
        for (int e = 0; e < 3; ++e) {
            int idx = t + 256 * e;          // 768 = 12*64
            int h = idx >> 6, m = idx & 63;
            tl[h * 66 + m] = __expf(tl[h * 66 + m] - nmx[h]);
        }
        #pragma unroll
        for (int k = 0; k < 3; ++k) { float a = alph[h0 + k]; acc2[k][0] *= a; acc2[k][1] *= a; }
        if (t < 240) { accF[0] *= alph[hF0]; accF[1] *= alph[hF1]; }
        __syncthreads();
        if (t < 12) {
            float ts = 0.f;
            for (int m = 0; m < 64; ++m) ts += tl[t * 66 + m];
            rsum[t] = rsum[t] * alph[t] + ts;
        }
        // -------- phase C: accumulate res_2d (from LDS) --------
        #pragma unroll 4
        for (int m = 0; m < 64; ++m) {
            float p0 = tl[(h0 + 0) * 66 + m];
            float p1 = tl[(h0 + 1) * 66 + m];
            float p2 = tl[(h0 + 2) * 66 + m];
            float x0 = x_l[cc * 65 + m];
            float x1 = x_l[(cc + 64) * 65 + m];
            acc2[0][0] += p0 * x0; acc2[0][1] += p0 * x1;
            acc2[1][0] += p1 * x0; acc2[1][1] += p1 * x1;
            acc2[2][0] += p2 * x0; acc2[2][1] += p2 * x1;
        }
        // -------- phase C2: accumulate res_scalar / res_pg (v from L2) --------
        if (t < 240) {
            #pragma unroll 4
            for (int m = 0; m < 64; ++m) {
                float pA = tl[hF0 * 66 + m];
                float pB = tl[hF1 * 66 + m];
                float vA = (j0 < 192)     ? vs[(size_t)(m0 + m) * 192 + j0]
                                          : vp[(size_t)(m0 + m) * 288 + (j0 - 192)];
                float vB = (j0 + 1 < 192) ? vs[(size_t)(m0 + m) * 192 + j0 + 1]
                                          : vp[(size_t)(m0 + m) * 288 + (j0 + 1 - 192)];
                accF[0] += pA * vA; accF[1] += pB * vB;
            }
        }
        __syncthreads();
    }

    // -------- epilogue --------
    if (t < 240) {
        float invA = 1.f / rsum[hF0];
        float invB = 1.f / rsum[hF1];
        if (j0 < 192) fin[(size_t)n * DOUT_ + j0] = accF[0] * invA;
        else          pg_l[j0 - 192] = accF[0] * invA;
        if (j0 + 1 < 192) fin[(size_t)n * DOUT_ + j0 + 1] = accF[1] * invB;
        else              pg_l[j0 + 1 - 192] = accF[1] * invB;
    }
    __syncthreads();
    if (t < 96) {
        int k = t;
        float c0 = pg_l[k]        - rt_l[9];
        float c1 = pg_l[96 + k]   - rt_l[10];
        float c2 = pg_l[192 + k]  - rt_l[11];
        // res_pl[a] = sum_c rot[n,c,a] * comp[c]; rot_l[c*3+a]
        float r0 = rt_l[0] * c0 + rt_l[3] * c1 + rt_l[6] * c2;
        float r1 = rt_l[1] * c0 + rt_l[4] * c1 + rt_l[7] * c2;
        float r2 = rt_l[2] * c0 + rt_l[5] * c1 + rt_l[8] * c2;
        fin[(size_t)n * DOUT_ + 192 + k] = r0;
        fin[(size_t)n * DOUT_ + 288 + k] = r1;
        fin[(size_t)n * DOUT_ + 384 + k] = r2;
        fin[(size_t)n * DOUT_ + 480 + k] = sqrtf(1e-8f + r0 * r0 + r1 * r1 + r2 * r2);
    }
    #pragma unroll
    for (int k = 0; k < 3; ++k) {
        float inv = 1.f / rsum[h0 + k];
        fin[(size_t)n * DOUT_ + 576 + (h0 + k) * 128 + cc]      = acc2[k][0] * inv;
        fin[(size_t)n * DOUT_ + 576 + (h0 + k) * 128 + cc + 64] = acc2[k][1] * inv;
    }
}

// ---------------- K3: out = final @ wo + bo  (1024x384, K=2112, fp32) ----------------
__global__ __launch_bounds__(256) void k_out(
    const float* __restrict__ fin, const float* __restrict__ wo, const float* __restrict__ bo,
    float* __restrict__ out)
{
    __shared__ float a_l[64 * 33];  // [k][m]
    __shared__ float b_l[64 * 33];  // [k][n]
    const int t = threadIdx.x;
    const int m0 = blockIdx.x * 32, n0 = blockIdx.y * 32;
    const int tx = t & 15, ty = t >> 4;
    float acc[2][2] = {{0.f, 0.f}, {0.f, 0.f}};
    for (int k0 = 0; k0 < DOUT_; k0 += 64) {
        #pragma unroll
        for (int r = 0; r < 8; ++r) {
            int f = t + 256 * r;            // 2048 = 32 rows * 64 k
            int row = f >> 6, c = f & 63;
            a_l[c * 33 + row] = fin[(size_t)(m0 + row) * DOUT_ + k0 + c];
        }
        #pragma unroll
        for (int r = 0; r < 8; ++r) {
            int f = t + 256 * r;            // 2048 = 64 k * 32 cols
            int row = f >> 5, c = f & 31;
            b_l[row * 33 + c] = wo[(size_t)(k0 + row) * NOUT_ + n0 + c];
        }
        __syncthreads();
        #pragma unroll 8
        for (int k = 0; k < 64; ++k) {
            float a0 = a_l[k * 33 + ty * 2], a1 = a_l[k * 33 + ty * 2 + 1];
            float b0 = b_l[k * 33 + tx * 2], b1 = b_l[k * 33 + tx * 2 + 1];
            acc[0][0] += a0 * b0; acc[0][1] += a0 * b1;
            acc[1][0] += a1 * b0; acc[1][1] += a1 * b1;
        }
        __syncthreads();
    }
    #pragma unroll
    for (int i = 0; i < 2; ++i)
        #pragma unroll
        for (int jj = 0; jj < 2; ++jj)
            out[(size_t)(m0 + ty * 2 + i) * NOUT_ + n0 + tx * 2 + jj] = acc[i][jj] + bo[n0 + tx * 2 + jj];
}

extern "C" void kernel_launch(void* const* d_in, const int* in_sizes, int n_in,
                              void* d_out, int out_size, void* d_ws, size_t ws_size,
                              hipStream_t stream) {
    const float* in1   = (const float*)d_in[0];
    const float* x2d   = (const float*)d_in[1];
    const float* mask  = (const float*)d_in[2];
    const float* rotm  = (const float*)d_in[3];
    const float* trans = (const float*)d_in[4];
    const float* wq    = (const float*)d_in[5];
    const float* bq    = (const float*)d_in[6];
    const float* wkv   = (const float*)d_in[7];
    const float* bkv   = (const float*)d_in[8];
    const float* wqp   = (const float*)d_in[9];
    const float* bqp   = (const float*)d_in[10];
    const float* wkvp  = (const float*)d_in[11];
    const float* bkvp  = (const float*)d_in[12];
    const float* w2d   = (const float*)d_in[13];
    const float* b2d   = (const float*)d_in[14];
    const float* tpw   = (const float*)d_in[15];
    const float* wo    = (const float*)d_in[16];
    const float* bo    = (const float*)d_in[17];
    float* out = (float*)d_out;

    float* ws = (float*)d_ws;
    float* qs = ws;                 // 1024*192
    float* ks = qs + 196608;        // 1024*192
    float* vs = ks + 196608;        // 1024*192
    float* qp = vs + 196608;        // 1024*144
    float* kp = qp + 147456;        // 1024*144
    float* vp = kp + 147456;        // 1024*288
    float* sq = vp + 294912;        // 1024*12
    float* sk = sq + 12288;         // 1024*12
    float* fin = sk + 12288;        // 1024*2112

    hipLaunchKernelGGL(k_proj, dim3(128), dim3(256), 0, stream,
        in1, rotm, trans, wq, bq, wkv, bkv, wqp, bqp, wkvp, bkvp,
        qs, ks, vs, qp, kp, vp, sq, sk);
    hipLaunchKernelGGL(k_attn, dim3(1024), dim3(256), 0, stream,
        x2d, mask, rotm, trans, w2d, b2d, tpw, qs, ks, vs, qp, kp, vp, sq, sk, fin);
    hipLaunchKernelGGL(k_out, dim3(32, 12), dim3(256), 0, stream, fin, wo, bo, out);
}

// Round 2
// 871.094 us; speedup vs baseline: 1.1071x; 1.1071x over previous
//
#include <hip/hip_runtime.h>
#include <math.h>

#define NN_ 1024
#define DOUT_ 2112
#define PSTR_ 2040   // partial row: 1536 res2d | 480 resF | 12 max | 12 sum

// ---------------- K1: yraw[1024][1152] = in1 @ [wq|wkv|wqp|wkvp] + bias ----------------
__global__ __launch_bounds__(256) void k_gemm1(
    const float* __restrict__ in1,
    const float* __restrict__ wq, const float* __restrict__ bq,
    const float* __restrict__ wkv, const float* __restrict__ bkv,
    const float* __restrict__ wqp, const float* __restrict__ bqp,
    const float* __restrict__ wkvp, const float* __restrict__ bkvp,
    float* __restrict__ yraw)
{
    __shared__ float a_l[64 * 36];
    __shared__ float b_l[32 * 68];
    const int t = threadIdx.x;
    const int m0 = blockIdx.x * 64, j0 = blockIdx.y * 64;
    const int tx = t & 15, ty = t >> 4;
    float acc[4][4] = {};
    for (int k0 = 0; k0 < 384; k0 += 32) {
        #pragma unroll
        for (int e = 0; e < 2; ++e) {
            int idx = t + 256 * e;
            int r = idx >> 3, c4 = (idx & 7) * 4;
            *(float4*)&a_l[r * 36 + c4] = *(const float4*)&in1[(size_t)(m0 + r) * 384 + k0 + c4];
        }
        #pragma unroll
        for (int e = 0; e < 2; ++e) {
            int idx = t + 256 * e;
            int r = idx >> 4, c4 = (idx & 15) * 4;
            int j = j0 + c4;
            const float* w; int ncol, jj;
            if (j < 192)      { w = wq;   ncol = 192; jj = j; }
            else if (j < 576) { w = wkv;  ncol = 384; jj = j - 192; }
            else if (j < 720) { w = wqp;  ncol = 144; jj = j - 576; }
            else              { w = wkvp; ncol = 432; jj = j - 720; }
            *(float4*)&b_l[r * 68 + c4] = *(const float4*)&w[(size_t)(k0 + r) * ncol + jj];
        }
        __syncthreads();
        #pragma unroll 8
        for (int k = 0; k < 32; ++k) {
            float4 bv = *(const float4*)&b_l[k * 68 + tx * 4];
            #pragma unroll
            for (int i = 0; i < 4; ++i) {
                float av = a_l[(ty * 4 + i) * 36 + k];
                acc[i][0] += av * bv.x; acc[i][1] += av * bv.y;
                acc[i][2] += av * bv.z; acc[i][3] += av * bv.w;
            }
        }
        __syncthreads();
    }
    int j = j0 + tx * 4;
    float4 bias;
    {
        const float* b; int jj;
        if (j < 192)      { b = bq;   jj = j; }
        else if (j < 576) { b = bkv;  jj = j - 192; }
        else if (j < 720) { b = bqp;  jj = j - 576; }
        else              { b = bkvp; jj = j - 720; }
        bias = *(const float4*)&b[jj];
    }
    #pragma unroll
    for (int i = 0; i < 4; ++i) {
        float4 o;
        o.x = acc[i][0] + bias.x; o.y = acc[i][1] + bias.y;
        o.z = acc[i][2] + bias.z; o.w = acc[i][3] + bias.w;
        *(float4*)&yraw[(size_t)(m0 + ty * 4 + i) * 1152 + j] = o;
    }
}

// ---------------- K2: rotations + packing ----------------
// kpack[n][352]: [0:192 ks(h*16+s)] [192:336 kp(a*48+h*4+p)] [336:348 sk(h)]
// vpack[n][480]: [0:192 vs(h*16+s)] [192:480 vp(a*96+h*8+p)]
__global__ __launch_bounds__(256) void k_rot(
    const float* __restrict__ yraw, const float* __restrict__ rotm, const float* __restrict__ trans,
    float* __restrict__ qp_arr, float* __restrict__ kpack, float* __restrict__ vpack,
    float* __restrict__ sq_arr)
{
    __shared__ float rt_l[4][12];
    const int t = threadIdx.x;
    const int n0 = blockIdx.x * 4;
    if (t < 48) {
        int n_ = t / 12, i = t % 12;
        rt_l[n_][i] = (i < 9) ? rotm[(n0 + n_) * 9 + i] : trans[(n0 + n_) * 3 + (i - 9)];
    }
    __syncthreads();
    const int n_ = t >> 6, l = t & 63;
    const int n = n0 + n_;
    const float* y = yraw + (size_t)n * 1152;
    const float* R = rt_l[n_];
    #pragma unroll
    for (int jj = 0; jj < 9; ++jj) {
        int o = l + 64 * jj;
        if (o < 144) {
            int a = o / 48, kk = o % 48;
            float v = R[9 + a] + R[a*3+0] * y[576 + kk] + R[a*3+1] * y[576 + 48 + kk] + R[a*3+2] * y[576 + 96 + kk];
            qp_arr[(size_t)n * 144 + o] = v;
        } else if (o < 288) {
            int o2 = o - 144;
            int a = o2 / 48, r2 = o2 % 48;
            int kk = (r2 >> 2) * 12 + (r2 & 3);
            float v = R[9 + a] + R[a*3+0] * y[720 + kk] + R[a*3+1] * y[720 + 144 + kk] + R[a*3+2] * y[720 + 288 + kk];
            kpack[(size_t)n * 352 + 192 + o2] = v;
        } else {
            int o3 = o - 288;
            int a = o3 / 96, r2 = o3 % 96;
            int kk = (r2 >> 3) * 12 + 4 + (r2 & 7);
            float v = R[9 + a] + R[a*3+0] * y[720 + kk] + R[a*3+1] * y[720 + 144 + kk] + R[a*3+2] * y[720 + 288 + kk];
            vpack[(size_t)n * 480 + 192 + o3] = v;
        }
    }
    #pragma unroll
    for (int jj = 0; jj < 3; ++jj) {
        int o = l + 64 * jj;  // 0..191
        int h = o >> 4, r2 = o & 15;
        kpack[(size_t)n * 352 + o] = y[192 + h * 32 + r2];
        vpack[(size_t)n * 480 + o] = y[192 + h * 32 + 16 + r2];
    }
    if (l < 24) {
        int which = l / 12, h = l % 12;
        int base = (which == 0) ? 576 : 720;
        int stride = (which == 0) ? 48 : 144;
        float s = 0.f;
        #pragma unroll
        for (int a = 0; a < 3; ++a) {
            #pragma unroll
            for (int p = 0; p < 4; ++p) {
                int kk = (which == 0) ? (h * 4 + p) : (h * 12 + p);
                float v = R[9 + a] + R[a*3+0] * y[base + kk] + R[a*3+1] * y[base + stride + kk] + R[a*3+2] * y[base + 2 * stride + kk];
                s += v * v;
            }
        }
        if (which == 0) sq_arr[(size_t)n * 12 + h] = s;
        else            kpack[(size_t)n * 352 + 336 + h] = s;
    }
}

// ---------------- K3: flash IPA, grid (1024 n, 2 msplit) ----------------
__global__ __launch_bounds__(256) void k_attn2(
    const float* __restrict__ x2d, const float* __restrict__ mask,
    const float* __restrict__ w2d, const float* __restrict__ b2d, const float* __restrict__ tpw,
    const float* __restrict__ yraw, const float* __restrict__ qp_arr,
    const float* __restrict__ kpack, const float* __restrict__ vpack,
    const float* __restrict__ sq_arr,
    float* __restrict__ part)
{
    __shared__ float w2_l[12 * 128];
    __shared__ float tl[12 * 68];
    __shared__ float qs_l[192], qp_l[144];
    __shared__ float sq_l[12], b2_l[12], pw_l[12];
    __shared__ float rmax_l[12], rsum_l[12], alph[12], nmx[12];

    const int t = threadIdx.x;
    const int n = blockIdx.x;
    const int ms = blockIdx.y;

    #pragma unroll
    for (int e = 0; e < 6; ++e) {
        int idx = t + 256 * e;
        int c = idx / 12, h = idx % 12;
        w2_l[h * 128 + c] = w2d[idx];
    }
    if (t < 192) qs_l[t] = yraw[(size_t)n * 1152 + t];
    if (t < 144) qp_l[t] = qp_arr[(size_t)n * 144 + t];
    if (t < 12) {
        sq_l[t] = sq_arr[(size_t)n * 12 + t];
        b2_l[t] = b2d[t];
        pw_l[t] = 0.13608276348795434f * log1pf(expf(tpw[t]));
        rmax_l[t] = -3.0e38f; rsum_l[t] = 0.f;
    }
    const float mask_n = mask[n];

    const int m_ = t >> 2, q_ = t & 3;        // phases A1/A2
    const int hg = t >> 7, cc = t & 127;      // phase C (res2d)
    const int j0 = 2 * t;                     // phase C2 (resF), t<240
    const int hC2 = (j0 < 192) ? (j0 >> 4) : (((j0 - 192) % 96) >> 3);
    float acc2[6] = {};
    float accF[2] = {};
    __syncthreads();

    for (int m0 = ms * 512; m0 < ms * 512 + 512; m0 += 64) {
        // ---- A1: att2d partial dots (x from global, w2 from LDS) ----
        float at2[12];
        #pragma unroll
        for (int h = 0; h < 12; ++h) at2[h] = 0.f;
        const float* xrow = x2d + ((size_t)n * NN_ + (m0 + m_)) * 128 + q_ * 32;
        #pragma unroll
        for (int i = 0; i < 8; ++i) {
            float4 xv = *(const float4*)&xrow[4 * i];
            #pragma unroll
            for (int h = 0; h < 12; ++h) {
                float4 wv = *(const float4*)&w2_l[h * 128 + q_ * 32 + 4 * i];
                at2[h] += xv.x * wv.x + xv.y * wv.y + xv.z * wv.z + xv.w * wv.w;
            }
        }
        #pragma unroll
        for (int h = 0; h < 12; ++h) {
            at2[h] += __shfl_xor(at2[h], 1);
            at2[h] += __shfl_xor(at2[h], 2);
        }
        // ---- A2: logits for 3 heads ----
        {
            const int mg = m0 + m_;
            const float mk = 100000.0f * (1.0f - mask_n * mask[mg]);
            const float* kr = kpack + (size_t)mg * 352;
            #pragma unroll
            for (int e = 0; e < 3; ++e) {
                int h = q_ * 3 + e;
                float d = 0.f;
                #pragma unroll
                for (int s4 = 0; s4 < 4; ++s4) {
                    float4 a = *(const float4*)&qs_l[h * 16 + 4 * s4];
                    float4 b = *(const float4*)&kr[h * 16 + 4 * s4];
                    d += a.x * b.x + a.y * b.y + a.z * b.z + a.w * b.w;
                }
                float qk = 0.f;
                #pragma unroll
                for (int a = 0; a < 3; ++a) {
                    float4 kv = *(const float4*)&kr[192 + a * 48 + h * 4];
                    float4 qv = *(const float4*)&qp_l[a * 48 + h * 4];
                    qk += qv.x * kv.x + qv.y * kv.y + qv.z * kv.z + qv.w * kv.w;
                }
                float dist2 = sq_l[h] + kr[336 + h] - 2.f * qk;
                tl[h * 68 + m_] = 0.14433756729740643f * d - 0.5f * pw_l[h] * dist2
                                + 0.57735026918962576f * (at2[h] + b2_l[h]) - mk;
            }
        }
        __syncthreads();
        // ---- B: parallel max (12 h x 16 lanes) ----
        if (t < 192) {
            int h = t >> 4, l = t & 15;
            float tm = fmaxf(fmaxf(tl[h * 68 + l], tl[h * 68 + l + 16]),
                             fmaxf(tl[h * 68 + l + 32], tl[h * 68 + l + 48]));
            tm = fmaxf(tm, __shfl_xor(tm, 1));
            tm = fmaxf(tm, __shfl_xor(tm, 2));
            tm = fmaxf(tm, __shfl_xor(tm, 4));
            tm = fmaxf(tm, __shfl_xor(tm, 8));
            if (l == 0) {
                float nm = fmaxf(rmax_l[h], tm);
                alph[h] = __expf(rmax_l[h] - nm);
                nmx[h] = nm; rmax_l[h] = nm;
            }
        }
        __syncthreads();
        // ---- exp in place + rescale accumulators ----
        #pragma unroll
        for (int e = 0; e < 3; ++e) {
            int idx = t + 256 * e;
            int h = idx >> 6, m = idx & 63;
            tl[h * 68 + m] = __expf(tl[h * 68 + m] - nmx[h]);
        }
        #pragma unroll
        for (int j2 = 0; j2 < 6; ++j2) acc2[j2] *= alph[hg * 6 + j2];
        if (t < 240) { float a = alph[hC2]; accF[0] *= a; accF[1] *= a; }
        __syncthreads();
        // ---- parallel sum ----
        if (t < 192) {
            int h = t >> 4, l = t & 15;
            float s = tl[h * 68 + l] + tl[h * 68 + l + 16] + tl[h * 68 + l + 32] + tl[h * 68 + l + 48];
            s += __shfl_xor(s, 1); s += __shfl_xor(s, 2);
            s += __shfl_xor(s, 4); s += __shfl_xor(s, 8);
            if (l == 0) rsum_l[h] = rsum_l[h] * alph[h] + s;
        }
        // ---- C: res2d accumulate (p broadcast f4, x from L2) ----
        {
            const float* xc = x2d + ((size_t)n * NN_ + m0) * 128 + cc;
            #pragma unroll 2
            for (int mc = 0; mc < 16; ++mc) {
                float4 p0 = *(const float4*)&tl[(hg * 6 + 0) * 68 + 4 * mc];
                float4 p1 = *(const float4*)&tl[(hg * 6 + 1) * 68 + 4 * mc];
                float4 p2 = *(const float4*)&tl[(hg * 6 + 2) * 68 + 4 * mc];
                float4 p3 = *(const float4*)&tl[(hg * 6 + 3) * 68 + 4 * mc];
                float4 p4 = *(const float4*)&tl[(hg * 6 + 4) * 68 + 4 * mc];
                float4 p5 = *(const float4*)&tl[(hg * 6 + 5) * 68 + 4 * mc];
                float x0 = xc[(size_t)(4 * mc + 0) * 128];
                float x1 = xc[(size_t)(4 * mc + 1) * 128];
                float x2v = xc[(size_t)(4 * mc + 2) * 128];
                float x3 = xc[(size_t)(4 * mc + 3) * 128];
                acc2[0] += p0.x * x0 + p0.y * x1 + p0.z * x2v + p0.w * x3;
                acc2[1] += p1.x * x0 + p1.y * x1 + p1.z * x2v + p1.w * x3;
                acc2[2] += p2.x * x0 + p2.y * x1 + p2.z * x2v + p2.w * x3;
                acc2[3] += p3.x * x0 + p3.y * x1 + p3.z * x2v + p3.w * x3;
                acc2[4] += p4.x * x0 + p4.y * x1 + p4.z * x2v + p4.w * x3;
                acc2[5] += p5.x * x0 + p5.y * x1 + p5.z * x2v + p5.w * x3;
            }
        }
        // ---- C2: resF accumulate (v packed f2) ----
        if (t < 240) {
            const float* vc = vpack + (size_t)m0 * 480 + j0;
            #pragma unroll 2
            for (int mc = 0; mc < 16; ++mc) {
                float4 p = *(const float4*)&tl[hC2 * 68 + 4 * mc];
                float2 v0 = *(const float2*)&vc[(size_t)(4 * mc + 0) * 480];
                float2 v1 = *(const float2*)&vc[(size_t)(4 * mc + 1) * 480];
                float2 v2 = *(const float2*)&vc[(size_t)(4 * mc + 2) * 480];
                float2 v3 = *(const float2*)&vc[(size_t)(4 * mc + 3) * 480];
                accF[0] += p.x * v0.x + p.y * v1.x + p.z * v2.x + p.w * v3.x;
                accF[1] += p.x * v0.y + p.y * v1.y + p.z * v2.y + p.w * v3.y;
            }
        }
        __syncthreads();
    }

    float* pr = part + ((size_t)ms * NN_ + n) * PSTR_;
    #pragma unroll
    for (int j2 = 0; j2 < 6; ++j2) pr[(hg * 6 + j2) * 128 + cc] = acc2[j2];
    if (t < 240) { pr[1536 + j0] = accF[0]; pr[1536 + j0 + 1] = accF[1]; }
    if (t < 12) { pr[2016 + t] = rmax_l[t]; pr[2028 + t] = rsum_l[t]; }
}

// ---------------- K4: merge 2 msplit partials + epilogue ----------------
__global__ __launch_bounds__(256) void k_merge(
    const float* __restrict__ part, const float* __restrict__ rotm, const float* __restrict__ trans,
    float* __restrict__ fin)
{
    __shared__ float w0_l[12], w1_l[12], pg_l[288], rt_l[12];
    const int t = threadIdx.x;
    const int n = blockIdx.x;
    const float* p0 = part + (size_t)n * PSTR_;
    const float* p1 = part + (size_t)(NN_ + n) * PSTR_;
    if (t < 12) {
        float m0v = p0[2016 + t], m1v = p1[2016 + t];
        float gm = fmaxf(m0v, m1v);
        float f0 = __expf(m0v - gm), f1 = __expf(m1v - gm);
        float gs = p0[2028 + t] * f0 + p1[2028 + t] * f1;
        w0_l[t] = f0 / gs; w1_l[t] = f1 / gs;
    }
    if (t >= 32 && t < 44) {
        int i = t - 32;
        rt_l[i] = (i < 9) ? rotm[n * 9 + i] : trans[n * 3 + i - 9];
    }
    __syncthreads();
    float* fr = fin + (size_t)n * DOUT_;
    #pragma unroll
    for (int e = 0; e < 6; ++e) {
        int idx = t + 256 * e;
        int h = idx >> 7;
        fr[576 + idx] = p0[idx] * w0_l[h] + p1[idx] * w1_l[h];
    }
    if (t < 240) {
        int j0 = 2 * t;
        int h = (j0 < 192) ? (j0 >> 4) : (((j0 - 192) % 96) >> 3);
        float a0 = p0[1536 + j0] * w0_l[h] + p1[1536 + j0] * w1_l[h];
        float a1 = p0[1537 + j0] * w0_l[h] + p1[1537 + j0] * w1_l[h];
        if (j0 < 192) { fr[j0] = a0; fr[j0 + 1] = a1; }
        else { pg_l[j0 - 192] = a0; pg_l[j0 - 191] = a1; }
    }
    __syncthreads();
    if (t < 96) {
        float c0 = pg_l[t] - rt_l[9];
        float c1 = pg_l[96 + t] - rt_l[10];
        float c2 = pg_l[192 + t] - rt_l[11];
        float r0 = rt_l[0] * c0 + rt_l[3] * c1 + rt_l[6] * c2;
        float r1 = rt_l[1] * c0 + rt_l[4] * c1 + rt_l[7] * c2;
        float r2 = rt_l[2] * c0 + rt_l[5] * c1 + rt_l[8] * c2;
        fr[192 + t] = r0; fr[288 + t] = r1; fr[384 + t] = r2;
        fr[480 + t] = sqrtf(1e-8f + r0 * r0 + r1 * r1 + r2 * r2);
    }
}

// ---------------- K5: out partials, split-K over 4 chunks of 528 ----------------
__global__ __launch_bounds__(256) void k_out(
    const float* __restrict__ fin, const float* __restrict__ wo,
    float* __restrict__ pout)
{
    __shared__ float a_l[64 * 52];
    __shared__ float b_l[48 * 68];
    const int t = threadIdx.x;
    const int m0 = blockIdx.x * 64, n0 = blockIdx.y * 64, kc = blockIdx.z;
    const int tx = t & 15, ty = t >> 4;
    float acc[4][4] = {};
    for (int k0 = kc * 528; k0 < kc * 528 + 528; k0 += 48) {
        #pragma unroll
        for (int e = 0; e < 3; ++e) {
            int idx = t + 256 * e;          // 768 f4 = 64 rows x 12 f4
            int r = idx / 12, c4 = (idx % 12) * 4;
            *(float4*)&a_l[r * 52 + c4] = *(const float4*)&fin[(size_t)(m0 + r) * DOUT_ + k0 + c4];
        }
        #pragma unroll
        for (int e = 0; e < 3; ++e) {
            int idx = t + 256 * e;          // 768 f4 = 48 rows x 16 f4
            int r = idx >> 4, c4 = (idx & 15) * 4;
            *(float4*)&b_l[r * 68 + c4] = *(const float4*)&wo[(size_t)(k0 + r) * 384 + n0 + c4];
        }
        __syncthreads();
        #pragma unroll 4
        for (int k = 0; k < 48; ++k) {
            float4 bv = *(const float4*)&b_l[k * 68 + tx * 4];
            #pragma unroll
            for (int i = 0; i < 4; ++i) {
                float av = a_l[(ty * 4 + i) * 52 + k];
                acc[i][0] += av * bv.x; acc[i][1] += av * bv.y;
                acc[i][2] += av * bv.z; acc[i][3] += av * bv.w;
            }
        }
        __syncthreads();
    }
    float* pr = pout + (size_t)kc * 393216;
    #pragma unroll
    for (int i = 0; i < 4; ++i) {
        float4 o;
        o.x = acc[i][0]; o.y = acc[i][1]; o.z = acc[i][2]; o.w = acc[i][3];
        *(float4*)&pr[(size_t)(m0 + ty * 4 + i) * 384 + n0 + tx * 4] = o;
    }
}

// ---------------- K6: sum split-K partials + bias ----------------
__global__ __launch_bounds__(256) void k_fin(
    const float* __restrict__ pout, const float* __restrict__ bo, float* __restrict__ out)
{
    int idx = blockIdx.x * 256 + threadIdx.x;   // f4 index, 98304 total
    float4 a = *(const float4*)&pout[(size_t)idx * 4];
    float4 b = *(const float4*)&pout[393216 + (size_t)idx * 4];
    float4 c = *(const float4*)&pout[786432 + (size_t)idx * 4];
    float4 d = *(const float4*)&pout[1179648 + (size_t)idx * 4];
    float4 bias = *(const float4*)&bo[(idx % 96) * 4];
    float4 o;
    o.x = a.x + b.x + c.x + d.x + bias.x;
    o.y = a.y + b.y + c.y + d.y + bias.y;
    o.z = a.z + b.z + c.z + d.z + bias.z;
    o.w = a.w + b.w + c.w + d.w + bias.w;
    *(float4*)&out[(size_t)idx * 4] = o;
}

extern "C" void kernel_launch(void* const* d_in, const int* in_sizes, int n_in,
                              void* d_out, int out_size, void* d_ws, size_t ws_size,
                              hipStream_t stream) {
    const float* in1   = (const float*)d_in[0];
    const float* x2d   = (const float*)d_in[1];
    const float* mask  = (const float*)d_in[2];
    const float* rotm  = (const float*)d_in[3];
    const float* trans = (const float*)d_in[4];
    const float* wq    = (const float*)d_in[5];
    const float* bq    = (const float*)d_in[6];
    const float* wkv   = (const float*)d_in[7];
    const float* bkv   = (const float*)d_in[8];
    const float* wqp   = (const float*)d_in[9];
    const float* bqp   = (const float*)d_in[10];
    const float* wkvp  = (const float*)d_in[11];
    const float* bkvp  = (const float*)d_in[12];
    const float* w2d   = (const float*)d_in[13];
    const float* b2d   = (const float*)d_in[14];
    const float* tpw   = (const float*)d_in[15];
    const float* wo    = (const float*)d_in[16];
    const float* bo    = (const float*)d_in[17];
    float* out = (float*)d_out;

    float* ws = (float*)d_ws;
    float* yraw   = ws;                    // 1,179,648
    float* qp_arr = yraw + 1179648;        //   147,456
    float* kpack  = qp_arr + 147456;       //   360,448
    float* vpack  = kpack + 360448;        //   491,520
    float* sq_arr = vpack + 491520;        //    12,288
    float* part   = sq_arr + 12288;        // 4,177,920 (2 x 1024 x 2040)
    float* fin    = part + 4177920;        // 2,162,688
    float* pout   = part;                  // reuse (1,572,864 <= 4,177,920)

    hipLaunchKernelGGL(k_gemm1, dim3(16, 18), dim3(256), 0, stream,
        in1, wq, bq, wkv, bkv, wqp, bqp, wkvp, bkvp, yraw);
    hipLaunchKernelGGL(k_rot, dim3(256), dim3(256), 0, stream,
        yraw, rotm, trans, qp_arr, kpack, vpack, sq_arr);
    hipLaunchKernelGGL(k_attn2, dim3(1024, 2), dim3(256), 0, stream,
        x2d, mask, w2d, b2d, tpw, yraw, qp_arr, kpack, vpack, sq_arr, part);
    hipLaunchKernelGGL(k_merge, dim3(1024), dim3(256), 0, stream,
        part, rotm, trans, fin);
    hipLaunchKernelGGL(k_out, dim3(16, 6, 4), dim3(256), 0, stream, fin, wo, pout);
    hipLaunchKernelGGL(k_fin, dim3(384), dim3(256), 0, stream, pout, bo, out);
}